// Round 1
// baseline (1028.957 us; speedup 1.0000x reference)
//
#include <hip/hip_runtime.h>
#include <stdint.h>

typedef unsigned short u16;
typedef __bf16 bf16x8 __attribute__((ext_vector_type(8)));
typedef float f32x4 __attribute__((ext_vector_type(4)));

#define T_TOK 8192      // B*S tokens
#define DM    1024      // d_model
#define DF    4096      // d_ff
#define NE    8         // experts
#define BM    128       // GEMM tile M
#define BK    64        // GEMM tile K (bf16 elems)
#define MAXT  136       // max total tiles: 16384/128 + NE

// ---- helpers ----------------------------------------------------------------

__device__ __forceinline__ u16 f2b(float f) {   // fp32 -> bf16 RNE
  union { float f; uint32_t u; } v; v.f = f;
  uint32_t r = (v.u + 0x7FFFu + ((v.u >> 16) & 1u)) >> 16;
  return (u16)r;
}

__device__ __forceinline__ void async16(const void* g, void* l) {
  // 16B/lane global->LDS DMA; LDS dest must be wave-uniform base + lane*16
  __builtin_amdgcn_global_load_lds((const __attribute__((address_space(1))) void*)g,
                                   (__attribute__((address_space(3))) void*)l, 16, 0, 0);
}

// ---- router: logits, top-2 softmax weights, bucket append, x->bf16 ----------

__global__ __launch_bounds__(256) void router_k(
    const float* __restrict__ x, const float* __restrict__ rw,
    const float* __restrict__ rb, u16* __restrict__ xb,
    float* __restrict__ wsl, int* __restrict__ bucket, int* __restrict__ counts)
{
  int lane = threadIdx.x & 63;
  int t = blockIdx.x * 4 + (threadIdx.x >> 6);   // one wave per token
  const float* xp = x + (size_t)t * DM;
  float acc[NE];
#pragma unroll
  for (int e = 0; e < NE; ++e) acc[e] = 0.f;
  for (int i = 0; i < DM / 64; ++i) {
    int idx = i * 64 + lane;
    float xv = xp[idx];
    xb[(size_t)t * DM + idx] = f2b(xv);          // fused x -> bf16
#pragma unroll
    for (int e = 0; e < NE; ++e) acc[e] += xv * rw[e * DM + idx];
  }
#pragma unroll
  for (int e = 0; e < NE; ++e) {
#pragma unroll
    for (int off = 32; off >= 1; off >>= 1) acc[e] += __shfl_xor(acc[e], off);
  }
  if (lane == 0) {
    float l[NE];
#pragma unroll
    for (int e = 0; e < NE; ++e) l[e] = acc[e] + rb[e];
    int i1 = 0;
#pragma unroll
    for (int e = 1; e < NE; ++e) if (l[e] > l[i1]) i1 = e;   // strict > : lowest idx on tie
    int i2 = (i1 == 0) ? 1 : 0;
#pragma unroll
    for (int e = 0; e < NE; ++e) if (e != i1 && l[e] > l[i2]) i2 = e;
    // softmax over {l1,l2} == softmax-then-renormalize of reference
    float e2 = expf(l[i2] - l[i1]);
    float wa = 1.f / (1.f + e2);
    wsl[2 * t]     = wa;
    wsl[2 * t + 1] = 1.f - wa;
    int p1 = atomicAdd(&counts[i1], 1); bucket[i1 * T_TOK + p1] = 2 * t;
    int p2 = atomicAdd(&counts[i2], 1); bucket[i2 * T_TOK + p2] = 2 * t + 1;
  }
}

// ---- fp32 -> bf16 weight convert (exact-size grid, 4 elems/thread) ----------

struct alignas(8) U16x4 { u16 x, y, z, w; };

__global__ __launch_bounds__(256) void cvt_k(const float* __restrict__ w,
                                             u16* __restrict__ o)
{
  int i = blockIdx.x * 256 + threadIdx.x;
  float4 v = ((const float4*)w)[i];
  U16x4 u; u.x = f2b(v.x); u.y = f2b(v.y); u.z = f2b(v.z); u.w = f2b(v.w);
  ((U16x4*)o)[i] = u;
}

// ---- tile prefix (1 thread; 8 experts) --------------------------------------

__global__ void toff_k(const int* __restrict__ counts, int* __restrict__ toff) {
  if (threadIdx.x == 0 && blockIdx.x == 0) {
    int a = 0;
    for (int e = 0; e < NE; ++e) { toff[e] = a; a += (counts[e] + BM - 1) >> 7; }
    toff[NE] = a;
  }
}

// ---- stage 1: H[slot, DF] = gelu( gather(xb) @ w1[e]^T + b1[e] ) ------------
// grid (DF/128, MAXT): x = f-slice (fastest -> same A-tile adjacent), y = tile

__global__ __launch_bounds__(256, 2) void stage1_k(
    const u16* __restrict__ xb, const u16* __restrict__ w1b,
    const float* __restrict__ b1, const int* __restrict__ bucket,
    const int* __restrict__ counts, const int* __restrict__ toff,
    u16* __restrict__ H)
{
  __shared__ __align__(16) u16 sA[BM * BK];
  __shared__ __align__(16) u16 sB[BM * BK];
  __shared__ int sSlot[BM];

  int fs = blockIdx.x;
  int tb = blockIdx.y;
  if (tb >= toff[NE]) return;
  int e = 0;
#pragma unroll
  for (int q = 1; q < NE; ++q) if (tb >= toff[q]) e = q;  // last match skips empties
  int ti = tb - toff[e];
  int cnt = counts[e];
  int tid = threadIdx.x;

  if (tid < BM) {
    int r = ti * BM + tid;
    sSlot[tid] = (r < cnt) ? bucket[e * T_TOK + r] : -1;
  }
  __syncthreads();

  int tokA[4];
#pragma unroll
  for (int c = 0; c < 4; ++c) {
    int s = sSlot[c * 32 + (tid >> 3)];
    tokA[c] = (s < 0) ? 0 : (s >> 1);
  }

  const u16* wB = w1b + ((size_t)e * DF + (size_t)fs * 128) * DM;

  int lane = tid & 63, wid = tid >> 6;
  int wm = wid >> 1, wn = wid & 1;
  int l15 = lane & 15;
  int kq = (lane >> 4) * 8;
  int colb = (tid & 7) * 8;
  int rowb = tid >> 3;

  f32x4 acc[4][4] = {};

  for (int k0 = 0; k0 < DM; k0 += BK) {
    __syncthreads();
#pragma unroll
    for (int c = 0; c < 4; ++c) {
      async16(xb + (size_t)tokA[c] * DM + k0 + colb, &sA[c * 2048 + tid * 8]);
      async16(wB + (size_t)(c * 32 + rowb) * DM + k0 + colb, &sB[c * 2048 + tid * 8]);
    }
    __syncthreads();
#pragma unroll
    for (int kk = 0; kk < BK; kk += 32) {
      bf16x8 af[4], bfr[4];
#pragma unroll
      for (int i = 0; i < 4; ++i)
        af[i] = *(const bf16x8*)&sA[(wm * 64 + i * 16 + l15) * BK + kk + kq];
#pragma unroll
      for (int j = 0; j < 4; ++j)
        bfr[j] = *(const bf16x8*)&sB[(wn * 64 + j * 16 + l15) * BK + kk + kq];
#pragma unroll
      for (int i = 0; i < 4; ++i)
#pragma unroll
        for (int j = 0; j < 4; ++j)
          acc[i][j] = __builtin_amdgcn_mfma_f32_16x16x32_bf16(af[i], bfr[j], acc[i][j], 0, 0, 0);
    }
  }

  int fbase = fs * 128;
#pragma unroll
  for (int i = 0; i < 4; ++i) {
    int mb = wm * 64 + i * 16 + (lane >> 4) * 4;
#pragma unroll
    for (int j = 0; j < 4; ++j) {
      int col = wn * 64 + j * 16 + l15;
      float bias = b1[e * DF + fbase + col];
#pragma unroll
      for (int r = 0; r < 4; ++r) {
        int slot = sSlot[mb + r];
        if (slot >= 0) {
          float v = acc[i][j][r] + bias;
          float g = 0.5f * v * (1.0f + erff(v * 0.70710678118654752f)); // exact gelu
          H[(size_t)slot * DF + fbase + col] = f2b(g);
        }
      }
    }
  }
}

// ---- stage 2: out[token] += w * ( gather(H) @ w2[e]^T + b2[e] ) -------------
// grid (DM/128, MAXT)

__global__ __launch_bounds__(256, 2) void stage2_k(
    const u16* __restrict__ H, const u16* __restrict__ w2b,
    const float* __restrict__ b2, const float* __restrict__ wsl,
    const int* __restrict__ bucket, const int* __restrict__ counts,
    const int* __restrict__ toff, float* __restrict__ out)
{
  __shared__ __align__(16) u16 sA[BM * BK];
  __shared__ __align__(16) u16 sB[BM * BK];
  __shared__ int sSlot[BM];

  int ds = blockIdx.x;
  int tb = blockIdx.y;
  if (tb >= toff[NE]) return;
  int e = 0;
#pragma unroll
  for (int q = 1; q < NE; ++q) if (tb >= toff[q]) e = q;
  int ti = tb - toff[e];
  int cnt = counts[e];
  int tid = threadIdx.x;

  if (tid < BM) {
    int r = ti * BM + tid;
    sSlot[tid] = (r < cnt) ? bucket[e * T_TOK + r] : -1;
  }
  __syncthreads();

  int rowA[4];
#pragma unroll
  for (int c = 0; c < 4; ++c) {
    int s = sSlot[c * 32 + (tid >> 3)];
    rowA[c] = (s < 0) ? 0 : s;      // slot 0 always valid/written
  }

  const u16* wB = w2b + ((size_t)e * DM + (size_t)ds * 128) * DF;

  int lane = tid & 63, wid = tid >> 6;
  int wm = wid >> 1, wn = wid & 1;
  int l15 = lane & 15;
  int kq = (lane >> 4) * 8;
  int colb = (tid & 7) * 8;
  int rowb = tid >> 3;

  f32x4 acc[4][4] = {};

  for (int k0 = 0; k0 < DF; k0 += BK) {
    __syncthreads();
#pragma unroll
    for (int c = 0; c < 4; ++c) {
      async16(H + (size_t)rowA[c] * DF + k0 + colb, &sA[c * 2048 + tid * 8]);
      async16(wB + (size_t)(c * 32 + rowb) * DF + k0 + colb, &sB[c * 2048 + tid * 8]);
    }
    __syncthreads();
#pragma unroll
    for (int kk = 0; kk < BK; kk += 32) {
      bf16x8 af[4], bfr[4];
#pragma unroll
      for (int i = 0; i < 4; ++i)
        af[i] = *(const bf16x8*)&sA[(wm * 64 + i * 16 + l15) * BK + kk + kq];
#pragma unroll
      for (int j = 0; j < 4; ++j)
        bfr[j] = *(const bf16x8*)&sB[(wn * 64 + j * 16 + l15) * BK + kk + kq];
#pragma unroll
      for (int i = 0; i < 4; ++i)
#pragma unroll
        for (int j = 0; j < 4; ++j)
          acc[i][j] = __builtin_amdgcn_mfma_f32_16x16x32_bf16(af[i], bfr[j], acc[i][j], 0, 0, 0);
    }
  }

  int dbase = ds * 128;
#pragma unroll
  for (int i = 0; i < 4; ++i) {
    int mb = wm * 64 + i * 16 + (lane >> 4) * 4;
#pragma unroll
    for (int j = 0; j < 4; ++j) {
      int col = wn * 64 + j * 16 + l15;
      float bias = b2[e * DM + dbase + col];
#pragma unroll
      for (int r = 0; r < 4; ++r) {
        int slot = sSlot[mb + r];
        if (slot >= 0) {
          float v = (acc[i][j][r] + bias) * wsl[slot];
          atomicAdd(&out[(size_t)(slot >> 1) * DM + dbase + col], v);
        }
      }
    }
  }
}

// ---- launch -----------------------------------------------------------------

extern "C" void kernel_launch(void* const* d_in, const int* in_sizes, int n_in,
                              void* d_out, int out_size, void* d_ws, size_t ws_size,
                              hipStream_t stream) {
  const float* x  = (const float*)d_in[0];
  const float* rw = (const float*)d_in[1];
  const float* rb = (const float*)d_in[2];
  const float* w1 = (const float*)d_in[3];
  const float* b1 = (const float*)d_in[4];
  const float* w2 = (const float*)d_in[5];
  const float* b2 = (const float*)d_in[6];
  float* out = (float*)d_out;

  char* ws = (char*)d_ws;
  size_t off = 0;
  auto alloc = [&](size_t bytes) -> void* {
    void* p = ws + off;
    off = (off + bytes + 255) & ~(size_t)255;
    return p;
  };
  u16*   xb     = (u16*)alloc((size_t)T_TOK * DM * 2);        // 16.8 MB
  u16*   w1b    = (u16*)alloc((size_t)NE * DF * DM * 2);      // 67.1 MB
  u16*   w2b    = (u16*)alloc((size_t)NE * DM * DF * 2);      // 67.1 MB
  u16*   H      = (u16*)alloc((size_t)(2 * T_TOK) * DF * 2);  // 134.2 MB
  float* wsl    = (float*)alloc((size_t)(2 * T_TOK) * 4);
  int*   bucket = (int*)alloc((size_t)NE * T_TOK * 4);
  int*   counts = (int*)alloc(256);
  int*   toff   = (int*)alloc(256);

  hipMemsetAsync(counts, 0, NE * sizeof(int), stream);
  hipMemsetAsync(out, 0, (size_t)out_size * sizeof(float), stream);

  router_k<<<T_TOK / 4, 256, 0, stream>>>(x, rw, rb, xb, wsl, bucket, counts);
  cvt_k<<<(NE * DF * DM) / (256 * 4), 256, 0, stream>>>(w1, w1b);
  cvt_k<<<(NE * DM * DF) / (256 * 4), 256, 0, stream>>>(w2, w2b);
  toff_k<<<1, 64, 0, stream>>>(counts, toff);
  stage1_k<<<dim3(DF / 128, MAXT), 256, 0, stream>>>(xb, w1b, b1, bucket, counts, toff, H);
  stage2_k<<<dim3(DM / 128, MAXT), 256, 0, stream>>>(H, w2b, b2, wsl, bucket, counts, toff, out);
}

// Round 2
// 994.162 us; speedup vs baseline: 1.0350x; 1.0350x over previous
//
#include <hip/hip_runtime.h>
#include <stdint.h>

typedef unsigned short u16;
typedef __bf16 bf16x8 __attribute__((ext_vector_type(8)));
typedef float f32x4 __attribute__((ext_vector_type(4)));

#define T_TOK 8192      // B*S tokens
#define DM    1024      // d_model
#define DF    4096      // d_ff
#define NE    8         // experts
#define BM    128       // GEMM tile M
#define BK    64        // GEMM tile K (bf16 elems)
#define MAXT  136       // max total tiles: 16384/128 + NE

// ---- helpers ----------------------------------------------------------------

__device__ __forceinline__ u16 f2b(float f) {   // fp32 -> bf16 RNE
  union { float f; uint32_t u; } v; v.f = f;
  uint32_t r = (v.u + 0x7FFFu + ((v.u >> 16) & 1u)) >> 16;
  return (u16)r;
}

__device__ __forceinline__ void async16(const void* g, void* l) {
  // 16B/lane global->LDS DMA; LDS dest must be wave-uniform base + lane*16
  __builtin_amdgcn_global_load_lds((const __attribute__((address_space(1))) void*)g,
                                   (__attribute__((address_space(3))) void*)l, 16, 0, 0);
}

// ---- router: logits, top-2 softmax weights, bucket append, x->bf16 ----------

__global__ __launch_bounds__(256) void router_k(
    const float* __restrict__ x, const float* __restrict__ rw,
    const float* __restrict__ rb, u16* __restrict__ xb,
    float* __restrict__ wsl, int* __restrict__ bucket, int* __restrict__ counts)
{
  int lane = threadIdx.x & 63;
  int t = blockIdx.x * 4 + (threadIdx.x >> 6);   // one wave per token
  const float* xp = x + (size_t)t * DM;
  float acc[NE];
#pragma unroll
  for (int e = 0; e < NE; ++e) acc[e] = 0.f;
  for (int i = 0; i < DM / 64; ++i) {
    int idx = i * 64 + lane;
    float xv = xp[idx];
    xb[(size_t)t * DM + idx] = f2b(xv);          // fused x -> bf16
#pragma unroll
    for (int e = 0; e < NE; ++e) acc[e] += xv * rw[e * DM + idx];
  }
#pragma unroll
  for (int e = 0; e < NE; ++e) {
#pragma unroll
    for (int off = 32; off >= 1; off >>= 1) acc[e] += __shfl_xor(acc[e], off);
  }
  if (lane == 0) {
    float l[NE];
#pragma unroll
    for (int e = 0; e < NE; ++e) l[e] = acc[e] + rb[e];
    int i1 = 0;
#pragma unroll
    for (int e = 1; e < NE; ++e) if (l[e] > l[i1]) i1 = e;   // strict > : lowest idx on tie
    int i2 = (i1 == 0) ? 1 : 0;
#pragma unroll
    for (int e = 0; e < NE; ++e) if (e != i1 && l[e] > l[i2]) i2 = e;
    // softmax over {l1,l2} == softmax-then-renormalize of reference
    float e2 = expf(l[i2] - l[i1]);
    float wa = 1.f / (1.f + e2);
    wsl[2 * t]     = wa;
    wsl[2 * t + 1] = 1.f - wa;
    int p1 = atomicAdd(&counts[i1], 1); bucket[i1 * T_TOK + p1] = 2 * t;
    int p2 = atomicAdd(&counts[i2], 1); bucket[i2 * T_TOK + p2] = 2 * t + 1;
  }
}

// ---- fp32 -> bf16 weight convert (exact-size grid, 4 elems/thread) ----------

struct alignas(8) U16x4 { u16 x, y, z, w; };

__global__ __launch_bounds__(256) void cvt_k(const float* __restrict__ w,
                                             u16* __restrict__ o)
{
  int i = blockIdx.x * 256 + threadIdx.x;
  float4 v = ((const float4*)w)[i];
  U16x4 u; u.x = f2b(v.x); u.y = f2b(v.y); u.z = f2b(v.z); u.w = f2b(v.w);
  ((U16x4*)o)[i] = u;
}

// ---- tile prefix (1 thread; 8 experts) --------------------------------------

__global__ void toff_k(const int* __restrict__ counts, int* __restrict__ toff) {
  if (threadIdx.x == 0 && blockIdx.x == 0) {
    int a = 0;
    for (int e = 0; e < NE; ++e) { toff[e] = a; a += (counts[e] + BM - 1) >> 7; }
    toff[NE] = a;
  }
}

// ---- stage 1: H[slot, DF] = gelu( gather(xb) @ w1[e]^T + b1[e] ) ------------
// grid (DF/128, MAXT): x = f-slice (fastest -> same A-tile adjacent), y = tile
// LDS layout XOR-swizzled: physical 16B-chunk p of row r holds global chunk
// p ^ (r & 7)  -> ds_read_b128 across 16 rows covers all 32 banks (no 16-way
// conflict; row stride is exactly 128 B = 32 banks otherwise).

__global__ __launch_bounds__(256, 2) void stage1_k(
    const u16* __restrict__ xb, const u16* __restrict__ w1b,
    const float* __restrict__ b1, const int* __restrict__ bucket,
    const int* __restrict__ counts, const int* __restrict__ toff,
    u16* __restrict__ H)
{
  __shared__ __align__(16) u16 sA[BM * BK];
  __shared__ __align__(16) u16 sB[BM * BK];
  __shared__ int sSlot[BM];

  int fs = blockIdx.x;
  int tb = blockIdx.y;
  if (tb >= toff[NE]) return;
  int e = 0;
#pragma unroll
  for (int q = 1; q < NE; ++q) if (tb >= toff[q]) e = q;  // last match skips empties
  int ti = tb - toff[e];
  int cnt = counts[e];
  int tid = threadIdx.x;

  if (tid < BM) {
    int r = ti * BM + tid;
    sSlot[tid] = (r < cnt) ? bucket[e * T_TOK + r] : -1;
  }
  __syncthreads();

  int tokA[4];
#pragma unroll
  for (int c = 0; c < 4; ++c) {
    int s = sSlot[c * 32 + (tid >> 3)];
    tokA[c] = (s < 0) ? 0 : (s >> 1);
  }

  const u16* wB = w1b + ((size_t)e * DF + (size_t)fs * 128) * DM;

  int lane = tid & 63, wid = tid >> 6;
  int wm = wid >> 1, wn = wid & 1;
  int l15 = lane & 15;
  int l7  = l15 & 7;
  int rowb = tid >> 3;
  // source k-offset swizzle: this thread fills physical chunk (tid&7) of row
  // (tid>>3)&... ; it must carry global chunk (tid&7) ^ (row&7)
  int swz = (((tid & 7) ^ ((tid >> 3) & 7))) * 8;

  f32x4 acc[4][4] = {};

  for (int k0 = 0; k0 < DM; k0 += BK) {
    __syncthreads();
#pragma unroll
    for (int c = 0; c < 4; ++c) {
      async16(xb + (size_t)tokA[c] * DM + k0 + swz, &sA[c * 2048 + tid * 8]);
      async16(wB + (size_t)(c * 32 + rowb) * DM + k0 + swz, &sB[c * 2048 + tid * 8]);
    }
    __syncthreads();
#pragma unroll
    for (int kk = 0; kk < BK; kk += 32) {
      int gbase = (kk >> 3) + (lane >> 4);          // logical chunk index [0,8)
      int offE  = ((gbase ^ l7) << 3);               // swizzled elem offset in row
      bf16x8 af[4], bfr[4];
#pragma unroll
      for (int i = 0; i < 4; ++i)
        af[i] = *(const bf16x8*)&sA[(wm * 64 + i * 16 + l15) * BK + offE];
#pragma unroll
      for (int j = 0; j < 4; ++j)
        bfr[j] = *(const bf16x8*)&sB[(wn * 64 + j * 16 + l15) * BK + offE];
#pragma unroll
      for (int i = 0; i < 4; ++i)
#pragma unroll
        for (int j = 0; j < 4; ++j)
          acc[i][j] = __builtin_amdgcn_mfma_f32_16x16x32_bf16(af[i], bfr[j], acc[i][j], 0, 0, 0);
    }
  }

  int fbase = fs * 128;
#pragma unroll
  for (int i = 0; i < 4; ++i) {
    int mb = wm * 64 + i * 16 + (lane >> 4) * 4;
#pragma unroll
    for (int j = 0; j < 4; ++j) {
      int col = wn * 64 + j * 16 + l15;
      float bias = b1[e * DF + fbase + col];
#pragma unroll
      for (int r = 0; r < 4; ++r) {
        int slot = sSlot[mb + r];
        if (slot >= 0) {
          float v = acc[i][j][r] + bias;
          float g = 0.5f * v * (1.0f + erff(v * 0.70710678118654752f)); // exact gelu
          H[(size_t)slot * DF + fbase + col] = f2b(g);
        }
      }
    }
  }
}

// ---- stage 2: out[token] += w * ( gather(H) @ w2[e]^T + b2[e] ) -------------
// grid (DM/128, MAXT)

__global__ __launch_bounds__(256, 2) void stage2_k(
    const u16* __restrict__ H, const u16* __restrict__ w2b,
    const float* __restrict__ b2, const float* __restrict__ wsl,
    const int* __restrict__ bucket, const int* __restrict__ counts,
    const int* __restrict__ toff, float* __restrict__ out)
{
  __shared__ __align__(16) u16 sA[BM * BK];
  __shared__ __align__(16) u16 sB[BM * BK];
  __shared__ int sSlot[BM];

  int ds = blockIdx.x;
  int tb = blockIdx.y;
  if (tb >= toff[NE]) return;
  int e = 0;
#pragma unroll
  for (int q = 1; q < NE; ++q) if (tb >= toff[q]) e = q;
  int ti = tb - toff[e];
  int cnt = counts[e];
  int tid = threadIdx.x;

  if (tid < BM) {
    int r = ti * BM + tid;
    sSlot[tid] = (r < cnt) ? bucket[e * T_TOK + r] : -1;
  }
  __syncthreads();

  int rowA[4];
#pragma unroll
  for (int c = 0; c < 4; ++c) {
    int s = sSlot[c * 32 + (tid >> 3)];
    rowA[c] = (s < 0) ? 0 : s;      // slot 0 always valid/written
  }

  const u16* wB = w2b + ((size_t)e * DM + (size_t)ds * 128) * DF;

  int lane = tid & 63, wid = tid >> 6;
  int wm = wid >> 1, wn = wid & 1;
  int l15 = lane & 15;
  int l7  = l15 & 7;
  int rowb = tid >> 3;
  int swz = (((tid & 7) ^ ((tid >> 3) & 7))) * 8;

  f32x4 acc[4][4] = {};

  for (int k0 = 0; k0 < DF; k0 += BK) {
    __syncthreads();
#pragma unroll
    for (int c = 0; c < 4; ++c) {
      async16(H + (size_t)rowA[c] * DF + k0 + swz, &sA[c * 2048 + tid * 8]);
      async16(wB + (size_t)(c * 32 + rowb) * DF + k0 + swz, &sB[c * 2048 + tid * 8]);
    }
    __syncthreads();
#pragma unroll
    for (int kk = 0; kk < BK; kk += 32) {
      int gbase = (kk >> 3) + (lane >> 4);
      int offE  = ((gbase ^ l7) << 3);
      bf16x8 af[4], bfr[4];
#pragma unroll
      for (int i = 0; i < 4; ++i)
        af[i] = *(const bf16x8*)&sA[(wm * 64 + i * 16 + l15) * BK + offE];
#pragma unroll
      for (int j = 0; j < 4; ++j)
        bfr[j] = *(const bf16x8*)&sB[(wn * 64 + j * 16 + l15) * BK + offE];
#pragma unroll
      for (int i = 0; i < 4; ++i)
#pragma unroll
        for (int j = 0; j < 4; ++j)
          acc[i][j] = __builtin_amdgcn_mfma_f32_16x16x32_bf16(af[i], bfr[j], acc[i][j], 0, 0, 0);
    }
  }

  int dbase = ds * 128;
#pragma unroll
  for (int i = 0; i < 4; ++i) {
    int mb = wm * 64 + i * 16 + (lane >> 4) * 4;
#pragma unroll
    for (int j = 0; j < 4; ++j) {
      int col = wn * 64 + j * 16 + l15;
      float bias = b2[e * DM + dbase + col];
#pragma unroll
      for (int r = 0; r < 4; ++r) {
        int slot = sSlot[mb + r];
        if (slot >= 0) {
          float v = (acc[i][j][r] + bias) * wsl[slot];
          atomicAdd(&out[(size_t)(slot >> 1) * DM + dbase + col], v);
        }
      }
    }
  }
}

// ---- launch -----------------------------------------------------------------

extern "C" void kernel_launch(void* const* d_in, const int* in_sizes, int n_in,
                              void* d_out, int out_size, void* d_ws, size_t ws_size,
                              hipStream_t stream) {
  const float* x  = (const float*)d_in[0];
  const float* rw = (const float*)d_in[1];
  const float* rb = (const float*)d_in[2];
  const float* w1 = (const float*)d_in[3];
  const float* b1 = (const float*)d_in[4];
  const float* w2 = (const float*)d_in[5];
  const float* b2 = (const float*)d_in[6];
  float* out = (float*)d_out;

  char* ws = (char*)d_ws;
  size_t off = 0;
  auto alloc = [&](size_t bytes) -> void* {
    void* p = ws + off;
    off = (off + bytes + 255) & ~(size_t)255;
    return p;
  };
  u16*   xb     = (u16*)alloc((size_t)T_TOK * DM * 2);        // 16.8 MB
  u16*   w1b    = (u16*)alloc((size_t)NE * DF * DM * 2);      // 67.1 MB
  u16*   w2b    = (u16*)alloc((size_t)NE * DM * DF * 2);      // 67.1 MB
  u16*   H      = (u16*)alloc((size_t)(2 * T_TOK) * DF * 2);  // 134.2 MB
  float* wsl    = (float*)alloc((size_t)(2 * T_TOK) * 4);
  int*   bucket = (int*)alloc((size_t)NE * T_TOK * 4);
  int*   counts = (int*)alloc(256);
  int*   toff   = (int*)alloc(256);

  hipMemsetAsync(counts, 0, NE * sizeof(int), stream);
  hipMemsetAsync(out, 0, (size_t)out_size * sizeof(float), stream);

  router_k<<<T_TOK / 4, 256, 0, stream>>>(x, rw, rb, xb, wsl, bucket, counts);
  cvt_k<<<(NE * DF * DM) / (256 * 4), 256, 0, stream>>>(w1, w1b);
  cvt_k<<<(NE * DM * DF) / (256 * 4), 256, 0, stream>>>(w2, w2b);
  toff_k<<<1, 64, 0, stream>>>(counts, toff);
  stage1_k<<<dim3(DF / 128, MAXT), 256, 0, stream>>>(xb, w1b, b1, bucket, counts, toff, H);
  stage2_k<<<dim3(DM / 128, MAXT), 256, 0, stream>>>(H, w2b, b2, wsl, bucket, counts, toff, out);
}